// Round 14
// baseline (208.123 us; speedup 1.0000x reference)
//
#include <hip/hip_runtime.h>
#include <math.h>

#define T_LEN 2048
#define B_SZ 4
#define D_MODEL 1024
#define NH 16
#define HD 64
#define BH_TOT (B_SZ*NH)

typedef __attribute__((ext_vector_type(8))) short bf16x8;
typedef __attribute__((ext_vector_type(4))) float f32x4;
typedef __attribute__((ext_vector_type(16))) float f32x16;
typedef __attribute__((ext_vector_type(8))) unsigned short u16x8;
typedef __attribute__((ext_vector_type(4))) unsigned short u16x4;

union U8 { unsigned int u[4]; bf16x8 v; };

static __device__ __forceinline__ unsigned short f2bf(float f) {
  unsigned int x = __float_as_uint(f);
  x += 0x7fffu + ((x >> 16) & 1u);
  return (unsigned short)(x >> 16);
}
static __device__ __forceinline__ float bf2f(unsigned short u) {
  return __uint_as_float(((unsigned int)u) << 16);
}
// async global->LDS DMA, 16B per lane; LDS dest = wave-uniform base + lane*16
static __device__ __forceinline__ void gload16(const void* g, void* l) {
  __builtin_amdgcn_global_load_lds((const __attribute__((address_space(1))) void*)g,
                                   (__attribute__((address_space(3))) void*)l, 16, 0, 0);
}

#define QS_SCALE 0.18033688011112042f   // (1/8) * log2(e)

// ---------------- fused fp32->bf16 convert of x, W_qkv, W_out + rope table ----------------
__global__ __launch_bounds__(256) void cvt3_kernel(
    const float* __restrict__ x, const float* __restrict__ wq, const float* __restrict__ wo,
    unsigned short* __restrict__ xb, unsigned short* __restrict__ wqb,
    unsigned short* __restrict__ wob, float2* __restrict__ tab) {
  const int i = blockIdx.x * 256 + threadIdx.x;
  const int N1 = T_LEN * B_SZ * D_MODEL / 8;
  const int N2 = N1 + 3 * D_MODEL * D_MODEL / 8;
  const int N3 = N2 + D_MODEL * D_MODEL / 8;
  if (i >= N3) {
    const int j = i - N3;                  // rope table: 2048 x 32 entries
    if (j < T_LEN * 32) {
      const int t = j >> 5, fi = j & 31;
      const float inv_freq = powf(10000.f, -(float)fi / 32.f);
      float s, c;
      sincosf((float)t * inv_freq, &s, &c);
      tab[j] = make_float2(c, s);
    }
    return;
  }
  const float* s; unsigned short* d; int off;
  if (i < N1)      { s = x;  d = xb;  off = i; }
  else if (i < N2) { s = wq; d = wqb; off = i - N1; }
  else             { s = wo; d = wob; off = i - N2; }
  const float4 a = ((const float4*)s)[off * 2];
  const float4 b = ((const float4*)s)[off * 2 + 1];
  u16x8 o;
  o[0] = f2bf(a.x); o[1] = f2bf(a.y); o[2] = f2bf(a.z); o[3] = f2bf(a.w);
  o[4] = f2bf(b.x); o[5] = f2bf(b.y); o[6] = f2bf(b.z); o[7] = f2bf(b.w);
  ((u16x8*)d)[off] = o;
}

// ---------------- 256x256 8-wave phase-pipelined QKV GEMM (mode-1 only) ----------------
// BK=64, 8 waves (2M x 4N), per-wave 128x64 out. 2 LDS K-tile buffers (128 KB).
// Per K-tile t (4 phases, one C-quadrant each): p0/p1 stage A-halves of t+1
// (other buffer); p2/p3 stage B-halves of t+2 (current buffer — its B was
// consumed into registers before the p0-end barrier, 2 barriers earlier).
// Counted vmcnt(4) ONCE per K-tile top (outstanding = B(t+1)'s 4 loads);
// raw s_barrier; NO sched_barrier (r7's confound, m141 anti-pattern).
__global__ __launch_bounds__(512, 1) void gemm256_qkv_kernel(
    const unsigned short* __restrict__ A, const unsigned short* __restrict__ W,
    const float* __restrict__ bias,
    unsigned short* __restrict__ qd, unsigned short* __restrict__ kd,
    unsigned short* __restrict__ vtd, const float2* __restrict__ tab)
{
  __shared__ unsigned short As[2][256 * 64];   // 64 KB
  __shared__ unsigned short Bs[2][256 * 64];   // 64 KB
  const int K = D_MODEL;                       // 1024
  const int tid = threadIdx.x;
  const int l = tid & 63, w = tid >> 6;        // 8 waves
  const int lq = l & 15, lg = l >> 4;
  const int wm = w >> 2, wn = w & 3;           // 2 x 4
  const int m0 = blockIdx.x * 256, n0 = blockIdx.y * 256;
  const int lrow = l >> 3;
  const int lcolb = ((l & 7) << 4) ^ (lrow << 4);   // pre-swizzled source col

  // stage one 128-row half-tile (2 gload16/thread; 8 waves cover 128 rows)
  auto stageA = [&](int kt, int half) {
    char* dst = (char*)As[kt & 1] + half * 16384;
    const size_t gr0 = (size_t)(m0 + half * 128);
#pragma unroll
    for (int c = 0; c < 2; ++c) {
      const int r0 = w * 16 + c * 8;
      gload16((const char*)A + ((gr0 + r0 + lrow) * (size_t)K + kt * 64) * 2 + lcolb,
              dst + r0 * 128);
    }
  };
  auto stageB = [&](int kt, int half) {
    char* dst = (char*)Bs[kt & 1] + half * 16384;
    const size_t gr0 = (size_t)(n0 + half * 128);
#pragma unroll
    for (int c = 0; c < 2; ++c) {
      const int r0 = w * 16 + c * 8;
      gload16((const char*)W + ((gr0 + r0 + lrow) * (size_t)K + kt * 64) * 2 + lcolb,
              dst + r0 * 128);
    }
  };

  f32x4 acc[8][4];
#pragma unroll
  for (int mt = 0; mt < 8; ++mt)
#pragma unroll
    for (int nt = 0; nt < 4; ++nt)
#pragma unroll
      for (int r2 = 0; r2 < 4; ++r2) acc[mt][nt][r2] = 0.f;

  const int nk = K >> 6;                       // 16
  // prologue: A(0), B(0), B(1) -> 12 loads/thread in flight
  stageA(0, 0); stageA(0, 1);
  stageB(0, 0); stageB(0, 1);
  stageB(1, 0); stageB(1, 1);

  for (int t = 0; t < nk; ++t) {
    const int cur = t & 1;
    // retire A(t),B(t); B(t+1)'s 4 loads stay in flight (T4 counted wait)
    if (t < nk - 1) { asm volatile("s_waitcnt vmcnt(4)" ::: "memory"); }
    else            { asm volatile("s_waitcnt vmcnt(0)" ::: "memory"); }
    __builtin_amdgcn_s_barrier();              // buf[cur] ready for all waves
    asm volatile("" ::: "memory");

    const char* Ac = (const char*)As[cur];
    const char* Bc = (const char*)Bs[cur];

    // B fragments for the whole K-tile, held in registers (8 ds_read_b128)
    bf16x8 bfr[4][2];
#pragma unroll
    for (int nt = 0; nt < 4; ++nt) {
      const int r = wn * 64 + nt * 16 + lq;
      const int x = (r & 7) << 4;
#pragma unroll
      for (int kc = 0; kc < 2; ++kc)
        bfr[nt][kc] = *(const bf16x8*)(Bc + r * 128 + ((kc * 64 + lg * 16) ^ x));
    }

#pragma unroll
    for (int p = 0; p < 4; ++p) {
      // this phase's A quadrant (4 ds_read_b128)
      bf16x8 af[2][2];
#pragma unroll
      for (int i = 0; i < 2; ++i) {
        const int r = wm * 128 + (2 * p + i) * 16 + lq;
        const int x = (r & 7) << 4;
#pragma unroll
        for (int kc = 0; kc < 2; ++kc)
          af[i][kc] = *(const bf16x8*)(Ac + r * 128 + ((kc * 64 + lg * 16) ^ x));
      }
      // this phase's half-tile prefetch
      if (p == 0 && t + 1 < nk) stageA(t + 1, 0);
      if (p == 1 && t + 1 < nk) stageA(t + 1, 1);
      if (p == 2 && t + 2 < nk) stageB(t + 2, 0);
      if (p == 3 && t + 2 < nk) stageB(t + 2, 1);

      // MFMA cluster: one C-quadrant x K=64 (16 MFMA)
      __builtin_amdgcn_s_setprio(1);
#pragma unroll
      for (int i = 0; i < 2; ++i)
#pragma unroll
        for (int nt = 0; nt < 4; ++nt)
#pragma unroll
          for (int kc = 0; kc < 2; ++kc)
            acc[2 * p + i][nt] =
                __builtin_amdgcn_mfma_f32_16x16x32_bf16(af[i][kc], bfr[nt][kc],
                                                        acc[2 * p + i][nt], 0, 0, 0);
      __builtin_amdgcn_s_setprio(0);

      asm volatile("" ::: "memory");           // pin this phase's LDS reads
      __builtin_amdgcn_s_barrier();            // phase boundary
    }
  }

  // epilogue: fused rope + scatter (lane: col=lq per nt; rows mt*16+lg*4+r2)
  const int nb = n0 + wn * 64;                 // 64-aligned -> one (which, head)
  const int which = nb >> 10;
  const int h = (nb >> 6) & (NH - 1);
  float bv[4];
#pragma unroll
  for (int nt = 0; nt < 4; ++nt) bv[nt] = bias[nb + nt * 16 + lq];

  if (which == 2) {
    // V: transposed scatter [bh][hd][t], no rope
#pragma unroll
    for (int nt = 0; nt < 4; ++nt) {
      const int hd = nt * 16 + lq;
#pragma unroll
      for (int mt = 0; mt < 8; ++mt) {
        const int mbase = m0 + wm * 128 + mt * 16;
        const int t = (mbase >> 2) + lg;
#pragma unroll
        for (int r2 = 0; r2 < 4; ++r2) {
          const int b = r2;                    // m = mbase + lg*4 + r2 -> b = r2
          vtd[((size_t)(b * NH + h) * HD + hd) * T_LEN + t] =
              f2bf(acc[mt][nt][r2] + bv[nt]);
        }
      }
    }
  } else {
    // Q/K: fused RoPE. Pairs (nt0,nt2) at angle idx lq, (nt1,nt3) at 16+lq.
    unsigned short* dst = (which == 0) ? qd : kd;
    const float sc = (which == 0) ? QS_SCALE : 1.0f;
#pragma unroll
    for (int mt = 0; mt < 8; ++mt) {
      const int mbase = m0 + wm * 128 + mt * 16;
      const int t = (mbase >> 2) + lg;         // uniform across r2
      const float2 cs0 = tab[t * 32 + lq];
      const float2 cs1 = tab[t * 32 + 16 + lq];
#pragma unroll
      for (int r2 = 0; r2 < 4; ++r2) {
        const int b = r2;
        const float v0 = acc[mt][0][r2] + bv[0];
        const float v1 = acc[mt][1][r2] + bv[1];
        const float v2 = acc[mt][2][r2] + bv[2];
        const float v3 = acc[mt][3][r2] + bv[3];
        const float o0 = (v0 * cs0.x - v2 * cs0.y) * sc;
        const float o2 = (v2 * cs0.x + v0 * cs0.y) * sc;
        const float o1 = (v1 * cs1.x - v3 * cs1.y) * sc;
        const float o3 = (v3 * cs1.x + v1 * cs1.y) * sc;
        unsigned short* pp = dst + ((size_t)(b * NH + h) * T_LEN + t) * HD;
        pp[lq]      = f2bf(o0);
        pp[16 + lq] = f2bf(o1);
        pp[32 + lq] = f2bf(o2);
        pp[48 + lq] = f2bf(o3);
      }
    }
  }
}

// ---------------- bf16 MFMA GEMM (r12): counted-vmcnt double-buffer, out-proj ----------------
__global__ __launch_bounds__(256, 2) void gemm_mfma_kernel(
    const unsigned short* __restrict__ A, const unsigned short* __restrict__ W,
    const float* __restrict__ bias, float* __restrict__ C,
    int M, int N, int K)
{
  __shared__ unsigned short As[2][128 * 64];   // [buf][row][64 bf16]
  __shared__ unsigned short Bs[2][128 * 64];
  const int tid = threadIdx.x;
  const int l = tid & 63, w = tid >> 6;
  const int lq = l & 15, lg = l >> 4;
  const int wm = w >> 1, wn = w & 1;
  const int m0 = blockIdx.x * 128, n0 = blockIdx.y * 128;   // m-fastest (r9)

  const int lrow = l >> 3;
  const int lcolb = ((l & 7) << 4) ^ (lrow << 4);   // pre-swizzled source col

  f32x4 acc[4][4];
#pragma unroll
  for (int mt = 0; mt < 4; ++mt)
#pragma unroll
    for (int nt = 0; nt < 4; ++nt)
#pragma unroll
      for (int r2 = 0; r2 < 4; ++r2) acc[mt][nt][r2] = 0.f;

  const int nk = K >> 6;                    // 16
  auto stage = [&](int kt, int buf) {
#pragma unroll
    for (int c = 0; c < 4; ++c) {
      const int r0 = w * 32 + c * 8;
      const int row = r0 + lrow;
      gload16((const char*)A + ((size_t)(m0 + row) * K + kt * 64) * 2 + lcolb,
              (char*)As[buf] + r0 * 128);
      gload16((const char*)W + ((size_t)(n0 + row) * K + kt * 64) * 2 + lcolb,
              (char*)Bs[buf] + r0 * 128);
    }
  };

  stage(0, 0);
  stage(1, 1);

  for (int kt = 0; kt < nk; ++kt) {
    const int cur = kt & 1;
    if (kt + 1 < nk) { asm volatile("s_waitcnt vmcnt(8)" ::: "memory"); }
    else             { asm volatile("s_waitcnt vmcnt(0)" ::: "memory"); }
    __builtin_amdgcn_s_barrier();          // buf[cur] ready for all waves

#pragma unroll
    for (int kc = 0; kc < 2; ++kc) {
      bf16x8 af[4], bfr[4];
#pragma unroll
      for (int mt = 0; mt < 4; ++mt) {
        const int r = wm * 64 + mt * 16 + lq;
        af[mt] = *(const bf16x8*)((const char*)As[cur] + r * 128 +
                                  ((kc * 64 + lg * 16) ^ ((r & 7) << 4)));
      }
#pragma unroll
      for (int nt = 0; nt < 4; ++nt) {
        const int r = wn * 64 + nt * 16 + lq;
        bfr[nt] = *(const bf16x8*)((const char*)Bs[cur] + r * 128 +
                                   ((kc * 64 + lg * 16) ^ ((r & 7) << 4)));
      }
#pragma unroll
      for (int mt = 0; mt < 4; ++mt)
#pragma unroll
        for (int nt = 0; nt < 4; ++nt)
          acc[mt][nt] = __builtin_amdgcn_mfma_f32_16x16x32_bf16(af[mt], bfr[nt], acc[mt][nt], 0, 0, 0);
    }

    asm volatile("" ::: "memory");         // pin ds_reads above this point
    __builtin_amdgcn_s_barrier();          // all waves done reading buf[cur]
    if (kt + 2 < nk) stage(kt + 2, cur);   // refill the buffer just freed
  }

#pragma unroll
  for (int nt = 0; nt < 4; ++nt) {
    const int n = n0 + wn * 64 + nt * 16 + lq;
    const float bv = bias[n];
#pragma unroll
    for (int mt = 0; mt < 4; ++mt)
#pragma unroll
      for (int r2 = 0; r2 < 4; ++r2) {
        const int m = m0 + wm * 64 + mt * 16 + lg * 4 + r2;
        C[(size_t)m * N + n] = acc[mt][nt][r2] + bv;
      }
  }
}

// ---------------- bf16 32x32-MFMA flash attention (r13, unchanged) ----------------
__global__ __launch_bounds__(256, 4) void attn_mfma_kernel(
    const unsigned short* __restrict__ Qb,   // [bh][t][64] bf16, pre-scaled log2e/8
    const unsigned short* __restrict__ Kb,   // [bh][t][64] bf16
    const unsigned short* __restrict__ Vt,   // [bh][64][2048] bf16 (transposed)
    unsigned short* __restrict__ ctx)        // (T, B, D) bf16
{
  __shared__ unsigned short Ks[2][64 * 64];  // [s][64 d] swizzled
  __shared__ unsigned short Vs[2][64 * 64];  // [d][64 s] swizzled
  const int tid = threadIdx.x;
  const int l = tid & 63;
  const int w = tid >> 6;
  const int lq = l & 31;                     // this lane's q row (and V^T d row)
  const int h = l >> 5;
  const int bh = blockIdx.x;
  const int qc = (T_LEN / 128 - 1) - blockIdx.y;   // tail-first dispatch
  const int b = bh >> 4, hh = bh & 15;
  const size_t tb = (size_t)bh * T_LEN;

  const int q0w = qc * 128 + w * 32;
  const int qg = q0w + lq;

  bf16x8 qf[4];
#pragma unroll
  for (int s = 0; s < 4; ++s)
    qf[s] = *(const bf16x8*)(Qb + (tb + qg) * HD + s * 16 + h * 8);

  f32x16 acc0, acc1;
#pragma unroll
  for (int r = 0; r < 16; ++r) { acc0[r] = 0.f; acc1[r] = 0.f; }
  float mrun = -1e30f, lsum = 0.f;

  const int lrow = l >> 3;
  const int lcolb = ((l & 7) << 4) ^ (lrow << 4);  // pre-swizzled source col
  const int last = 2 * qc + 1;                     // >= 1 always

  auto stageT = [&](int t, int buf) {
    const int sn = t * 64;
#pragma unroll
    for (int c = 0; c < 2; ++c) {
      const int r0 = w * 16 + c * 8;
      const int row = r0 + lrow;
      gload16((const char*)Kb + ((tb + sn + row) * HD) * 2 + lcolb,
              (char*)Ks[buf] + r0 * 128);
      gload16((const char*)Vt + (((size_t)bh * HD + row) * T_LEN + sn) * 2 + lcolb,
              (char*)Vs[buf] + r0 * 128);
    }
  };

  stageT(0, 0);
  stageT(1, 1);

  for (int kbi = 0; kbi <= last; ++kbi) {
    const int s0 = kbi * 64;
    const int cur = kbi & 1;

    if (kbi < last) { asm volatile("s_waitcnt vmcnt(4)" ::: "memory"); }
    else            { asm volatile("s_waitcnt vmcnt(0)" ::: "memory"); }
    __builtin_amdgcn_s_barrier();
    asm volatile("" ::: "memory");

    const int dmax = q0w + 31 - s0;
    if (dmax >= 0) {
      const char* Kc = (const char*)Ks[cur];
      const char* Vc = (const char*)Vs[cur];
      const bool st1 = (dmax >= 32);
      const bool maskN = (s0 + 63 > q0w);

      f32x16 sv0, sv1;
#pragma unroll
      for (int r = 0; r < 16; ++r) { sv0[r] = -1e30f; sv1[r] = -1e30f; }
      {
        f32x16 z;
#pragma unroll
        for (int r = 0; r < 16; ++r) z[r] = 0.f;
        const int krow = lq;
        const int kswz = (krow & 7) << 4;
        __builtin_amdgcn_s_setprio(1);
#pragma unroll
        for (int s = 0; s < 4; ++s) {
          bf16x8 ka = *(const bf16x8*)(Kc + krow * 128 + ((s * 32 + h * 16) ^ kswz));
          z = __builtin_amdgcn_mfma_f32_32x32x16_bf16(ka, qf[s], z, 0, 0, 0);
        }
        __builtin_amdgcn_s_setprio(0);
        sv0 = z;
      }
      if (st1) {
        f32x16 z;
#pragma unroll
        for (int r = 0; r < 16; ++r) z[r] = 0.f;
        const int krow = 32 + lq;
        const int kswz = (krow & 7) << 4;
        __builtin_amdgcn_s_setprio(1);
#pragma unroll
        for (int s = 0; s < 4; ++s) {
          bf16x8 ka = *(const bf16x8*)(Kc + krow * 128 + ((s * 32 + h * 16) ^ kswz));
          z = __builtin_amdgcn_mfma_f32_32x32x16_bf16(ka, qf[s], z, 0, 0, 0);
        }
        __builtin_amdgcn_s_setprio(0);
        sv1 = z;
      }

      if (maskN) {
#pragma unroll
        for (int r = 0; r < 16; ++r) {
          const int sl = (r & 3) + 8 * (r >> 2) + 4 * h;
          if (s0 + sl > qg)      sv0[r] = -1e30f;
          if (s0 + 32 + sl > qg) sv1[r] = -1e30f;
        }
      }

      float pm[4];
#pragma unroll
      for (int j = 0; j < 4; ++j) pm[j] = fmaxf(sv0[j], sv1[j]);
#pragma unroll
      for (int r = 4; r < 16; ++r) pm[r & 3] = fmaxf(pm[r & 3], fmaxf(sv0[r], sv1[r]));
      float pmax = fmaxf(fmaxf(pm[0], pm[1]), fmaxf(pm[2], pm[3]));
      pmax = fmaxf(pmax, __shfl_xor(pmax, 32));

      if (!__all(pmax - mrun <= 8.0f)) {
        const float mnew = fmaxf(mrun, pmax);
        const float alpha = exp2f(mrun - mnew);
        lsum *= alpha;
#pragma unroll
        for (int r = 0; r < 16; ++r) { acc0[r] *= alpha; acc1[r] *= alpha; }
        mrun = mnew;
      }

      float s4[4] = {0.f, 0.f, 0.f, 0.f};
#pragma unroll
      for (int r = 0; r < 16; ++r) { sv0[r] = exp2f(sv0[r] - mrun); s4[r & 3] += sv0[r]; }
      if (st1) {
#pragma unroll
        for (int r = 0; r < 16; ++r) { sv1[r] = exp2f(sv1[r] - mrun); s4[r & 3] += sv1[r]; }
      }
      float ps = (s4[0] + s4[1]) + (s4[2] + s4[3]);
      ps += __shfl_xor(ps, 32);
      lsum += ps;

      unsigned int u0[4][2], u1[4][2];
#pragma unroll
      for (int a = 0; a < 4; ++a) {
        asm("v_cvt_pk_bf16_f32 %0, %1, %2" : "=v"(u0[a][0]) : "v"(sv0[4*a]),   "v"(sv0[4*a+1]));
        asm("v_cvt_pk_bf16_f32 %0, %1, %2" : "=v"(u0[a][1]) : "v"(sv0[4*a+2]), "v"(sv0[4*a+3]));
      }
      if (st1) {
#pragma unroll
        for (int a = 0; a < 4; ++a) {
          asm("v_cvt_pk_bf16_f32 %0, %1, %2" : "=v"(u1[a][0]) : "v"(sv1[4*a]),   "v"(sv1[4*a+1]));
          asm("v_cvt_pk_bf16_f32 %0, %1, %2" : "=v"(u1[a][1]) : "v"(sv1[4*a+2]), "v"(sv1[4*a+3]));
        }
      }

      const int vswz0 = (lq & 7) << 4;
#pragma unroll
      for (int st = 0; st < 2; ++st) {
        if (st == 1 && !st1) break;
#pragma unroll
        for (int cc = 0; cc < 2; ++cc) {
          unsigned int x0 = st ? u1[2*cc][0] : u0[2*cc][0];
          unsigned int y0 = st ? u1[2*cc+1][0] : u0[2*cc+1][0];
          unsigned int x1 = st ? u1[2*cc][1] : u0[2*cc][1];
          unsigned int y1 = st ? u1[2*cc+1][1] : u0[2*cc+1][1];
          asm("v_permlane32_swap_b32 %0, %1" : "+v"(x0), "+v"(y0));
          asm("v_permlane32_swap_b32 %0, %1" : "+v"(x1), "+v"(y1));
          U8 pf;
          pf.u[0] = x0; pf.u[1] = x1; pf.u[2] = y0; pf.u[3] = y1;
          const int soff = st * 64 + cc * 32 + h * 16;
          __builtin_amdgcn_s_setprio(1);
          {
            bf16x8 va = *(const bf16x8*)(Vc + lq * 128 + (soff ^ vswz0));
            acc0 = __builtin_amdgcn_mfma_f32_32x32x16_bf16(va, pf.v, acc0, 0, 0, 0);
          }
          {
            const int row = 32 + lq;
            bf16x8 va = *(const bf16x8*)(Vc + row * 128 + (soff ^ ((row & 7) << 4)));
            acc1 = __builtin_amdgcn_mfma_f32_32x32x16_bf16(va, pf.v, acc1, 0, 0, 0);
          }
          __builtin_amdgcn_s_setprio(0);
        }
      }
    }

    asm volatile("" ::: "memory");
    __builtin_amdgcn_s_barrier();
    if (kbi + 2 <= last) stageT(kbi + 2, cur);
  }

  const float linv = 1.f / lsum;
  unsigned short* orow = ctx + ((size_t)qg * B_SZ + b) * D_MODEL + hh * HD;
#pragma unroll
  for (int g = 0; g < 4; ++g) {
    u16x4 o0, o1;
#pragma unroll
    for (int j = 0; j < 4; ++j) {
      o0[j] = f2bf(acc0[4*g + j] * linv);
      o1[j] = f2bf(acc1[4*g + j] * linv);
    }
    *(u16x4*)(orow + 8*g + 4*h)      = o0;
    *(u16x4*)(orow + 32 + 8*g + 4*h) = o1;
  }
}

extern "C" void kernel_launch(void* const* d_in, const int* in_sizes, int n_in,
                              void* d_out, int out_size, void* d_ws, size_t ws_size,
                              hipStream_t stream) {
  const float* x    = (const float*)d_in[0];
  const float* Wqkv = (const float*)d_in[2];
  const float* bqkv = (const float*)d_in[3];
  const float* Wout = (const float*)d_in[4];
  const float* bout = (const float*)d_in[5];
  float* out = (float*)d_out;

  char* wsb = (char*)d_ws;
  unsigned short* xb    = (unsigned short*)(wsb);                  // 16 MiB
  unsigned short* wqkvb = (unsigned short*)(wsb + (16ull << 20));  // 6 MiB
  unsigned short* woutb = (unsigned short*)(wsb + (22ull << 20));  // 2 MiB
  unsigned short* qb    = (unsigned short*)(wsb + (24ull << 20));  // 16 MiB
  unsigned short* kb    = (unsigned short*)(wsb + (40ull << 20));  // 16 MiB
  unsigned short* vt    = (unsigned short*)(wsb + (56ull << 20));  // 16 MiB (transposed V)
  unsigned short* ctxb  = (unsigned short*)(wsb + (72ull << 20));  // 16 MiB
  float2* tab           = (float2*)(wsb + (88ull << 20));          // 512 KiB rope table

  const int ncvt = T_LEN*B_SZ*D_MODEL/8 + 3*D_MODEL*D_MODEL/8 + D_MODEL*D_MODEL/8
                 + T_LEN * 32;
  cvt3_kernel<<<(ncvt + 255)/256, 256, 0, stream>>>(x, Wqkv, Wout, xb, wqkvb, woutb, tab);

  // QKV GEMM (256² 8-wave phase pipeline) with fused rope/scatter epilogue
  dim3 g1((T_LEN * B_SZ) / 256, 3 * D_MODEL / 256);   // 32 x 12
  gemm256_qkv_kernel<<<g1, 512, 0, stream>>>(xb, wqkvb, bqkv, qb, kb, vt, tab);

  dim3 g2(BH_TOT, T_LEN / 128);
  attn_mfma_kernel<<<g2, 256, 0, stream>>>(qb, kb, vt, ctxb);

  // out-projection: r12 128² counted-vmcnt kernel (proven)
  dim3 g3((T_LEN * B_SZ) / 128, D_MODEL / 128);
  gemm_mfma_kernel<<<g3, 256, 0, stream>>>(ctxb, woutb, bout, out,
                                           T_LEN * B_SZ, D_MODEL, D_MODEL);
}

// Round 15
// 179.166 us; speedup vs baseline: 1.1616x; 1.1616x over previous
//
#include <hip/hip_runtime.h>
#include <math.h>

#define T_LEN 2048
#define B_SZ 4
#define D_MODEL 1024
#define NH 16
#define HD 64
#define BH_TOT (B_SZ*NH)

typedef __attribute__((ext_vector_type(8))) short bf16x8;
typedef __attribute__((ext_vector_type(4))) float f32x4;
typedef __attribute__((ext_vector_type(16))) float f32x16;
typedef __attribute__((ext_vector_type(8))) unsigned short u16x8;
typedef __attribute__((ext_vector_type(4))) unsigned short u16x4;

union U8 { unsigned int u[4]; bf16x8 v; };

static __device__ __forceinline__ unsigned short f2bf(float f) {
  unsigned int x = __float_as_uint(f);
  x += 0x7fffu + ((x >> 16) & 1u);
  return (unsigned short)(x >> 16);
}
static __device__ __forceinline__ float bf2f(unsigned short u) {
  return __uint_as_float(((unsigned int)u) << 16);
}
// async global->LDS DMA, 16B per lane; LDS dest = wave-uniform base + lane*16
static __device__ __forceinline__ void gload16(const void* g, void* l) {
  __builtin_amdgcn_global_load_lds((const __attribute__((address_space(1))) void*)g,
                                   (__attribute__((address_space(3))) void*)l, 16, 0, 0);
}

#define QS_SCALE 0.18033688011112042f   // (1/8) * log2(e)

// ---------------- fused fp32->bf16 convert of x, W_qkv, W_out + rope table ----------------
__global__ __launch_bounds__(256) void cvt3_kernel(
    const float* __restrict__ x, const float* __restrict__ wq, const float* __restrict__ wo,
    unsigned short* __restrict__ xb, unsigned short* __restrict__ wqb,
    unsigned short* __restrict__ wob, float2* __restrict__ tab) {
  const int i = blockIdx.x * 256 + threadIdx.x;
  const int N1 = T_LEN * B_SZ * D_MODEL / 8;
  const int N2 = N1 + 3 * D_MODEL * D_MODEL / 8;
  const int N3 = N2 + D_MODEL * D_MODEL / 8;
  if (i >= N3) {
    const int j = i - N3;                  // rope table: 2048 x 32 entries
    if (j < T_LEN * 32) {
      const int t = j >> 5, fi = j & 31;
      const float inv_freq = powf(10000.f, -(float)fi / 32.f);
      float s, c;
      sincosf((float)t * inv_freq, &s, &c);
      tab[j] = make_float2(c, s);
    }
    return;
  }
  const float* s; unsigned short* d; int off;
  if (i < N1)      { s = x;  d = xb;  off = i; }
  else if (i < N2) { s = wq; d = wqb; off = i - N1; }
  else             { s = wo; d = wob; off = i - N2; }
  const float4 a = ((const float4*)s)[off * 2];
  const float4 b = ((const float4*)s)[off * 2 + 1];
  u16x8 o;
  o[0] = f2bf(a.x); o[1] = f2bf(a.y); o[2] = f2bf(a.z); o[3] = f2bf(a.w);
  o[4] = f2bf(b.x); o[5] = f2bf(b.y); o[6] = f2bf(b.z); o[7] = f2bf(b.w);
  ((u16x8*)d)[off] = o;
}

// ---------------- bf16 MFMA GEMM: C = A(MxK) * W(NxK)^T + bias ----------------
// 128x128 tile, BK=64, 4 waves (2x2). DOUBLE-BUFFERED global_load_lds staging
// with COUNTED vmcnt(8) (T4): tile t+1's 8 loads stay in flight across the
// barrier; raw s_barrier (no compiler vmcnt(0) drain); no sched_barrier.
// m-fastest grid + r9-winning config otherwise. (Session best: r12 = 179.8 µs;
// 2-phase-with-drain r6, 256² r7/r14 all measured slower at these shapes.)
// mode 0: fp32 C[m*N+n]
// mode 1: bf16 scatter with FUSED ROPE: q (scaled QS), k -> [bh][t][hd];
//         v -> TRANSPOSED [bh][hd][t].
__global__ __launch_bounds__(256, 2) void gemm_mfma_kernel(
    const unsigned short* __restrict__ A, const unsigned short* __restrict__ W,
    const float* __restrict__ bias, float* __restrict__ C,
    int M, int N, int K, int mode,
    unsigned short* __restrict__ qd, unsigned short* __restrict__ kd,
    unsigned short* __restrict__ vtd, const float2* __restrict__ tab)
{
  __shared__ unsigned short As[2][128 * 64];   // [buf][row][64 bf16]
  __shared__ unsigned short Bs[2][128 * 64];
  const int tid = threadIdx.x;
  const int l = tid & 63, w = tid >> 6;
  const int lq = l & 15, lg = l >> 4;
  const int wm = w >> 1, wn = w & 1;
  const int m0 = blockIdx.x * 128, n0 = blockIdx.y * 128;   // m-fastest (r9)

  const int lrow = l >> 3;
  const int lcolb = ((l & 7) << 4) ^ (lrow << 4);   // pre-swizzled source col

  f32x4 acc[4][4];
#pragma unroll
  for (int mt = 0; mt < 4; ++mt)
#pragma unroll
    for (int nt = 0; nt < 4; ++nt)
#pragma unroll
      for (int r2 = 0; r2 < 4; ++r2) acc[mt][nt][r2] = 0.f;

  const int nk = K >> 6;                    // 16
  // stage one K-tile (8 gload16/thread: 4 A-rows + 4 B-rows)
  auto stage = [&](int kt, int buf) {
#pragma unroll
    for (int c = 0; c < 4; ++c) {
      const int r0 = w * 32 + c * 8;
      const int row = r0 + lrow;
      gload16((const char*)A + ((size_t)(m0 + row) * K + kt * 64) * 2 + lcolb,
              (char*)As[buf] + r0 * 128);
      gload16((const char*)W + ((size_t)(n0 + row) * K + kt * 64) * 2 + lcolb,
              (char*)Bs[buf] + r0 * 128);
    }
  };

  // prologue: tiles 0 and 1 in flight (16 loads/thread outstanding)
  stage(0, 0);
  stage(1, 1);

  for (int kt = 0; kt < nk; ++kt) {
    const int cur = kt & 1;
    // retire tile kt's 8 loads; tile kt+1's 8 stay in flight (never drain to 0
    // in steady state — T4)
    if (kt + 1 < nk) { asm volatile("s_waitcnt vmcnt(8)" ::: "memory"); }
    else             { asm volatile("s_waitcnt vmcnt(0)" ::: "memory"); }
    __builtin_amdgcn_s_barrier();          // buf[cur] ready for all waves

#pragma unroll
    for (int kc = 0; kc < 2; ++kc) {
      bf16x8 af[4], bfr[4];
#pragma unroll
      for (int mt = 0; mt < 4; ++mt) {
        const int r = wm * 64 + mt * 16 + lq;
        af[mt] = *(const bf16x8*)((const char*)As[cur] + r * 128 +
                                  ((kc * 64 + lg * 16) ^ ((r & 7) << 4)));
      }
#pragma unroll
      for (int nt = 0; nt < 4; ++nt) {
        const int r = wn * 64 + nt * 16 + lq;
        bfr[nt] = *(const bf16x8*)((const char*)Bs[cur] + r * 128 +
                                   ((kc * 64 + lg * 16) ^ ((r & 7) << 4)));
      }
#pragma unroll
      for (int mt = 0; mt < 4; ++mt)
#pragma unroll
        for (int nt = 0; nt < 4; ++nt)
          acc[mt][nt] = __builtin_amdgcn_mfma_f32_16x16x32_bf16(af[mt], bfr[nt], acc[mt][nt], 0, 0, 0);
    }

    asm volatile("" ::: "memory");         // pin ds_reads above this point
    __builtin_amdgcn_s_barrier();          // all waves done reading buf[cur]
    if (kt + 2 < nk) stage(kt + 2, cur);   // refill the buffer just freed
  }

  if (mode == 0) {
#pragma unroll
    for (int nt = 0; nt < 4; ++nt) {
      const int n = n0 + wn * 64 + nt * 16 + lq;
      const float bv = bias[n];
#pragma unroll
      for (int mt = 0; mt < 4; ++mt)
#pragma unroll
        for (int r2 = 0; r2 < 4; ++r2) {
          const int m = m0 + wm * 64 + mt * 16 + lg * 4 + r2;
          C[(size_t)m * N + n] = acc[mt][nt][r2] + bv;
        }
    }
  } else {
    const int nb = n0 + wn * 64;             // 64-aligned -> one (which, head)
    const int which = nb >> 10;
    const int h = (nb >> 6) & (NH - 1);
    float bv[4];
#pragma unroll
    for (int nt = 0; nt < 4; ++nt) bv[nt] = bias[nb + nt * 16 + lq];

    if (which == 2) {
      // V: transposed scatter [bh][hd][t], no rope
#pragma unroll
      for (int nt = 0; nt < 4; ++nt) {
        const int hd = nt * 16 + lq;
#pragma unroll
        for (int mt = 0; mt < 4; ++mt) {
          const int mbase = m0 + wm * 64 + mt * 16;
          const int t = (mbase >> 2) + lg;
#pragma unroll
          for (int r2 = 0; r2 < 4; ++r2) {
            const int b = r2;                // m = mbase + lg*4 + r2 -> b = r2
            vtd[((size_t)(b * NH + h) * HD + hd) * T_LEN + t] =
                f2bf(acc[mt][nt][r2] + bv[nt]);
          }
        }
      }
    } else {
      // Q/K: fused RoPE. Pairs (nt0,nt2) at angle idx lq, (nt1,nt3) at 16+lq.
      unsigned short* dst = (which == 0) ? qd : kd;
      const float sc = (which == 0) ? QS_SCALE : 1.0f;
#pragma unroll
      for (int mt = 0; mt < 4; ++mt) {
        const int mbase = m0 + wm * 64 + mt * 16;
        const int t = (mbase >> 2) + lg;     // uniform across r2
        const float2 cs0 = tab[t * 32 + lq];
        const float2 cs1 = tab[t * 32 + 16 + lq];
#pragma unroll
        for (int r2 = 0; r2 < 4; ++r2) {
          const int b = r2;
          const float v0 = acc[mt][0][r2] + bv[0];
          const float v1 = acc[mt][1][r2] + bv[1];
          const float v2 = acc[mt][2][r2] + bv[2];
          const float v3 = acc[mt][3][r2] + bv[3];
          const float o0 = (v0 * cs0.x - v2 * cs0.y) * sc;
          const float o2 = (v2 * cs0.x + v0 * cs0.y) * sc;
          const float o1 = (v1 * cs1.x - v3 * cs1.y) * sc;
          const float o3 = (v3 * cs1.x + v1 * cs1.y) * sc;
          unsigned short* p = dst + ((size_t)(b * NH + h) * T_LEN + t) * HD;
          p[lq]      = f2bf(o0);
          p[16 + lq] = f2bf(o1);
          p[32 + lq] = f2bf(o2);
          p[48 + lq] = f2bf(o3);
        }
      }
    }
  }
}

// ---------------- bf16 32x32-MFMA flash attention (r11/r12 config) ----------------
// Lane's q = l&31 for softmax AND output; defer-max (T13); pmax/ps reductions
// use explicit 4-accumulator trees.
__global__ __launch_bounds__(256, 4) void attn_mfma_kernel(
    const unsigned short* __restrict__ Qb,   // [bh][t][64] bf16, pre-scaled log2e/8
    const unsigned short* __restrict__ Kb,   // [bh][t][64] bf16
    const unsigned short* __restrict__ Vt,   // [bh][64][2048] bf16 (transposed)
    unsigned short* __restrict__ ctx)        // (T, B, D) bf16
{
  __shared__ unsigned short Ks[2][64 * 64];  // [s][64 d] swizzled
  __shared__ unsigned short Vs[2][64 * 64];  // [d][64 s] swizzled
  const int tid = threadIdx.x;
  const int l = tid & 63;
  const int w = tid >> 6;
  const int lq = l & 31;                     // this lane's q row (and V^T d row)
  const int h = l >> 5;
  const int bh = blockIdx.x;
  const int qc = (T_LEN / 128 - 1) - blockIdx.y;   // tail-first dispatch
  const int b = bh >> 4, hh = bh & 15;
  const size_t tb = (size_t)bh * T_LEN;

  const int q0w = qc * 128 + w * 32;
  const int qg = q0w + lq;

  bf16x8 qf[4];
#pragma unroll
  for (int s = 0; s < 4; ++s)
    qf[s] = *(const bf16x8*)(Qb + (tb + qg) * HD + s * 16 + h * 8);

  f32x16 acc0, acc1;
#pragma unroll
  for (int r = 0; r < 16; ++r) { acc0[r] = 0.f; acc1[r] = 0.f; }
  float mrun = -1e30f, lsum = 0.f;

  const int lrow = l >> 3;
  const int lcolb = ((l & 7) << 4) ^ (lrow << 4);  // pre-swizzled source col
  const int last = 2 * qc + 1;

#pragma unroll
  for (int c = 0; c < 2; ++c) {
    const int r0 = w * 16 + c * 8;
    const int row = r0 + lrow;
    gload16((const char*)Kb + ((tb + row) * HD) * 2 + lcolb, (char*)Ks[0] + r0 * 128);
    gload16((const char*)Vt + (((size_t)bh * HD + row) * T_LEN) * 2 + lcolb,
            (char*)Vs[0] + r0 * 128);
  }
  __syncthreads();

  for (int kbi = 0; kbi <= last; ++kbi) {
    const int s0 = kbi * 64;
    const int cur = kbi & 1;

    if (kbi < last) {
      const int sn = s0 + 64;
#pragma unroll
      for (int c = 0; c < 2; ++c) {
        const int r0 = w * 16 + c * 8;
        const int row = r0 + lrow;
        gload16((const char*)Kb + ((tb + sn + row) * HD) * 2 + lcolb,
                (char*)Ks[cur ^ 1] + r0 * 128);
        gload16((const char*)Vt + (((size_t)bh * HD + row) * T_LEN + sn) * 2 + lcolb,
                (char*)Vs[cur ^ 1] + r0 * 128);
      }
    }

    const int dmax = q0w + 31 - s0;
    if (dmax >= 0) {
      const char* Kc = (const char*)Ks[cur];
      const char* Vc = (const char*)Vs[cur];
      const bool st1 = (dmax >= 32);
      const bool maskN = (s0 + 63 > q0w);

      f32x16 sv0, sv1;
#pragma unroll
      for (int r = 0; r < 16; ++r) { sv0[r] = -1e30f; sv1[r] = -1e30f; }
      {
        f32x16 z;
#pragma unroll
        for (int r = 0; r < 16; ++r) z[r] = 0.f;
        const int krow = lq;
        const int kswz = (krow & 7) << 4;
        __builtin_amdgcn_s_setprio(1);
#pragma unroll
        for (int s = 0; s < 4; ++s) {
          bf16x8 ka = *(const bf16x8*)(Kc + krow * 128 + ((s * 32 + h * 16) ^ kswz));
          z = __builtin_amdgcn_mfma_f32_32x32x16_bf16(ka, qf[s], z, 0, 0, 0);
        }
        __builtin_amdgcn_s_setprio(0);
        sv0 = z;
      }
      if (st1) {
        f32x16 z;
#pragma unroll
        for (int r = 0; r < 16; ++r) z[r] = 0.f;
        const int krow = 32 + lq;
        const int kswz = (krow & 7) << 4;
        __builtin_amdgcn_s_setprio(1);
#pragma unroll
        for (int s = 0; s < 4; ++s) {
          bf16x8 ka = *(const bf16x8*)(Kc + krow * 128 + ((s * 32 + h * 16) ^ kswz));
          z = __builtin_amdgcn_mfma_f32_32x32x16_bf16(ka, qf[s], z, 0, 0, 0);
        }
        __builtin_amdgcn_s_setprio(0);
        sv1 = z;
      }

      if (maskN) {
#pragma unroll
        for (int r = 0; r < 16; ++r) {
          const int sl = (r & 3) + 8 * (r >> 2) + 4 * h;
          if (s0 + sl > qg)      sv0[r] = -1e30f;
          if (s0 + 32 + sl > qg) sv1[r] = -1e30f;
        }
      }

      // tile max: 4-accumulator tree (dependent chain 32 -> 8+2)
      float pm[4];
#pragma unroll
      for (int j = 0; j < 4; ++j) pm[j] = fmaxf(sv0[j], sv1[j]);
#pragma unroll
      for (int r = 4; r < 16; ++r) pm[r & 3] = fmaxf(pm[r & 3], fmaxf(sv0[r], sv1[r]));
      float pmax = fmaxf(fmaxf(pm[0], pm[1]), fmaxf(pm[2], pm[3]));
      pmax = fmaxf(pmax, __shfl_xor(pmax, 32));

      // defer-max (T13): rescale only when max grew past the threshold
      if (!__all(pmax - mrun <= 8.0f)) {
        const float mnew = fmaxf(mrun, pmax);
        const float alpha = exp2f(mrun - mnew);
        lsum *= alpha;
#pragma unroll
        for (int r = 0; r < 16; ++r) { acc0[r] *= alpha; acc1[r] *= alpha; }
        mrun = mnew;
      }

      // exp2 + sum: 4-accumulator tree for ps
      float s4[4] = {0.f, 0.f, 0.f, 0.f};
#pragma unroll
      for (int r = 0; r < 16; ++r) { sv0[r] = exp2f(sv0[r] - mrun); s4[r & 3] += sv0[r]; }
      if (st1) {
#pragma unroll
        for (int r = 0; r < 16; ++r) { sv1[r] = exp2f(sv1[r] - mrun); s4[r & 3] += sv1[r]; }
      }
      float ps = (s4[0] + s4[1]) + (s4[2] + s4[3]);
      ps += __shfl_xor(ps, 32);
      lsum += ps;

      unsigned int u0[4][2], u1[4][2];
#pragma unroll
      for (int a = 0; a < 4; ++a) {
        asm("v_cvt_pk_bf16_f32 %0, %1, %2" : "=v"(u0[a][0]) : "v"(sv0[4*a]),   "v"(sv0[4*a+1]));
        asm("v_cvt_pk_bf16_f32 %0, %1, %2" : "=v"(u0[a][1]) : "v"(sv0[4*a+2]), "v"(sv0[4*a+3]));
      }
      if (st1) {
#pragma unroll
        for (int a = 0; a < 4; ++a) {
          asm("v_cvt_pk_bf16_f32 %0, %1, %2" : "=v"(u1[a][0]) : "v"(sv1[4*a]),   "v"(sv1[4*a+1]));
          asm("v_cvt_pk_bf16_f32 %0, %1, %2" : "=v"(u1[a][1]) : "v"(sv1[4*a+2]), "v"(sv1[4*a+3]));
        }
      }

      const int vswz0 = (lq & 7) << 4;
#pragma unroll
      for (int st = 0; st < 2; ++st) {
        if (st == 1 && !st1) break;
#pragma unroll
        for (int cc = 0; cc < 2; ++cc) {
          unsigned int x0 = st ? u1[2*cc][0] : u0[2*cc][0];
          unsigned int y0 = st ? u1[2*cc+1][0] : u0[2*cc+1][0];
          unsigned int x1 = st ? u1[2*cc][1] : u0[2*cc][1];
          unsigned int y1 = st ? u1[2*cc+1][1] : u0[2*cc+1][1];
          asm("v_permlane32_swap_b32 %0, %1" : "+v"(x0), "+v"(y0));
          asm("v_permlane32_swap_b32 %0, %1" : "+v"(x1), "+v"(y1));
          U8 pf;
          pf.u[0] = x0; pf.u[1] = x1; pf.u[2] = y0; pf.u[3] = y1;
          const int soff = st * 64 + cc * 32 + h * 16;
          __builtin_amdgcn_s_setprio(1);
          {
            bf16x8 va = *(const bf16x8*)(Vc + lq * 128 + (soff ^ vswz0));
            acc0 = __builtin_amdgcn_mfma_f32_32x32x16_bf16(va, pf.v, acc0, 0, 0, 0);
          }
          {
            const int row = 32 + lq;
            bf16x8 va = *(const bf16x8*)(Vc + row * 128 + (soff ^ ((row & 7) << 4)));
            acc1 = __builtin_amdgcn_mfma_f32_32x32x16_bf16(va, pf.v, acc1, 0, 0, 0);
          }
          __builtin_amdgcn_s_setprio(0);
        }
      }
    }

    __syncthreads();
  }

  const float linv = 1.f / lsum;
  unsigned short* orow = ctx + ((size_t)qg * B_SZ + b) * D_MODEL + hh * HD;
#pragma unroll
  for (int g = 0; g < 4; ++g) {
    u16x4 o0, o1;
#pragma unroll
    for (int j = 0; j < 4; ++j) {
      o0[j] = f2bf(acc0[4*g + j] * linv);
      o1[j] = f2bf(acc1[4*g + j] * linv);
    }
    *(u16x4*)(orow + 8*g + 4*h)      = o0;
    *(u16x4*)(orow + 32 + 8*g + 4*h) = o1;
  }
}

extern "C" void kernel_launch(void* const* d_in, const int* in_sizes, int n_in,
                              void* d_out, int out_size, void* d_ws, size_t ws_size,
                              hipStream_t stream) {
  const float* x    = (const float*)d_in[0];
  const float* Wqkv = (const float*)d_in[2];
  const float* bqkv = (const float*)d_in[3];
  const float* Wout = (const float*)d_in[4];
  const float* bout = (const float*)d_in[5];
  float* out = (float*)d_out;

  char* wsb = (char*)d_ws;
  unsigned short* xb    = (unsigned short*)(wsb);                  // 16 MiB
  unsigned short* wqkvb = (unsigned short*)(wsb + (16ull << 20));  // 6 MiB
  unsigned short* woutb = (unsigned short*)(wsb + (22ull << 20));  // 2 MiB
  unsigned short* qb    = (unsigned short*)(wsb + (24ull << 20));  // 16 MiB
  unsigned short* kb    = (unsigned short*)(wsb + (40ull << 20));  // 16 MiB
  unsigned short* vt    = (unsigned short*)(wsb + (56ull << 20));  // 16 MiB (transposed V)
  unsigned short* ctxb  = (unsigned short*)(wsb + (72ull << 20));  // 16 MiB
  float2* tab           = (float2*)(wsb + (88ull << 20));          // 512 KiB rope table

  const int ncvt = T_LEN*B_SZ*D_MODEL/8 + 3*D_MODEL*D_MODEL/8 + D_MODEL*D_MODEL/8
                 + T_LEN * 32;
  cvt3_kernel<<<(ncvt + 255)/256, 256, 0, stream>>>(x, Wqkv, Wout, xb, wqkvb, woutb, tab);

  // QKV GEMM with fused rope/scatter epilogue; m-fastest grid (r9/r11 winner)
  dim3 g1((T_LEN * B_SZ) / 128, 3 * D_MODEL / 128);
  gemm_mfma_kernel<<<g1, 256, 0, stream>>>(xb, wqkvb, bqkv, nullptr,
                                           T_LEN * B_SZ, 3 * D_MODEL, D_MODEL, 1,
                                           qb, kb, vt, tab);

  dim3 g2(BH_TOT, T_LEN / 128);
  attn_mfma_kernel<<<g2, 256, 0, stream>>>(qb, kb, vt, ctxb);

  dim3 g3((T_LEN * B_SZ) / 128, D_MODEL / 128);
  gemm_mfma_kernel<<<g3, 256, 0, stream>>>(ctxb, woutb, bout, out,
                                           T_LEN * B_SZ, D_MODEL, D_MODEL, 0,
                                           nullptr, nullptr, nullptr, tab);
}